// Round 4
// baseline (441.234 us; speedup 1.0000x reference)
//
#include <hip/hip_runtime.h>
#include <math.h>

// ContextualNeuronPool: B=2,S=2048,K=8,POOL=512,DM=1024,DFF=4096,MD=64
// f32 inputs/outputs; internal GEMMs in bf16 MFMA.
#define T_    4096   // B*S tokens
#define K_    8
#define POOL_ 512
#define DM_   1024
#define DFF_  4096
#define MD_   64
#define KC_   576    // 512 (pool) + 64 (mod) combined contraction dim
#define NSPLIT 4     // k_selmod split-K factor

typedef __bf16 bf16x8 __attribute__((ext_vector_type(8)));
typedef __bf16 bf16x4 __attribute__((ext_vector_type(4)));
typedef float  f32x4  __attribute__((ext_vector_type(4)));

typedef __attribute__((address_space(1))) const void g_void;
typedef __attribute__((address_space(3))) void s_void;

__device__ __forceinline__ void async_ld16(const void* g, void* s) {
    __builtin_amdgcn_global_load_lds((g_void*)g, (s_void*)s, 16, 0, 0);
}
__device__ __forceinline__ float gelu_exact(float g) {
    return 0.5f * g * (1.f + erff(g * 0.70710678118654752f));
}

// ---------------------------------------------------------------------------
// Binning: counting sort of the 32768 (token,k) pairs by pool index.
// ---------------------------------------------------------------------------
__global__ __launch_bounds__(256) void k_hist(const int* __restrict__ sel,
                                              int* __restrict__ counts) {
    int i = blockIdx.x * 256 + threadIdx.x;
    if (i < T_ * K_) atomicAdd(&counts[sel[i]], 1);
}

__global__ __launch_bounds__(512) void k_scan(const int* __restrict__ counts,
                                              int* __restrict__ offsets,
                                              int* __restrict__ cursor) {
    __shared__ int s[512];
    const int t = threadIdx.x;
    const int c = counts[t];
    s[t] = c;
    __syncthreads();
    for (int d = 1; d < 512; d <<= 1) {
        int v = (t >= d) ? s[t - d] : 0;
        __syncthreads();
        s[t] += v;
        __syncthreads();
    }
    offsets[t] = s[t] - c;
    cursor[t]  = s[t] - c;
    if (t == 511) offsets[512] = s[511];
}

__global__ __launch_bounds__(256) void k_scatter(const int* __restrict__ sel,
                                                 int* __restrict__ cursor,
                                                 int* __restrict__ bucket) {
    int i = blockIdx.x * 256 + threadIdx.x;
    if (i < T_ * K_) {
        int p = sel[i];
        int pos = atomicAdd(&cursor[p], 1);
        bucket[pos] = i;
    }
}

// ---------------------------------------------------------------------------
// K1: expert-grouped sel_mod, split-K x4. Block (p, slice):
//     Yp[slice][pair][m] = dot(x[token][k0:k0+256], cm_w[p*64+m][k0:k0+256])
//     (no bias here; cm_b folded into k_wdense). 8 blocks/CU.
// ---------------------------------------------------------------------------
__global__ __launch_bounds__(256, 8) void k_selmod(
    const float* __restrict__ x, const float* __restrict__ cm_w,
    const int* __restrict__ bucket, const int* __restrict__ offsets,
    float* __restrict__ Yp)
{
    const int p     = blockIdx.x;
    const int slice = blockIdx.y;
    const int tid   = threadIdx.x;
    __shared__ __align__(16) __bf16 Xl[64][72];
    __shared__ __align__(16) __bf16 Wl[64][72];

    const int off = offsets[p];
    const int n   = min(offsets[p + 1] - off, 1024);
    if (n == 0) return;

    const int wave = tid >> 6, lane = tid & 63, quad = lane >> 4, l15 = lane & 15;
    const int srow = tid & 63;
    const int c0   = (tid >> 6) * 16;     // 16-col staging group
    const int k0   = slice * (DM_ / NSPLIT);

    const float* wrow = cm_w + (long)(p * 64 + srow) * DM_ + k0;
    float* Yo = Yp + (long)slice * ((long)T_ * K_ * MD_);

    for (int base = 0; base < n; base += 64) {
        f32x4 acc[4] = {};
        int li = base + srow; if (li >= n) li = n - 1;    // clamp: dup stage row
        const float* xrow = x + (long)(bucket[off + li] >> 3) * DM_ + k0;

        for (int kc = 0; kc < DM_ / NSPLIT; kc += 64) {
            const float4* xs = (const float4*)(xrow + kc + c0);
            const float4* ws = (const float4*)(wrow + kc + c0);
            #pragma unroll
            for (int u = 0; u < 4; ++u) {
                float4 xv = xs[u], wv = ws[u];
                bf16x4 xb, wb;
                xb[0]=(__bf16)xv.x; xb[1]=(__bf16)xv.y; xb[2]=(__bf16)xv.z; xb[3]=(__bf16)xv.w;
                wb[0]=(__bf16)wv.x; wb[1]=(__bf16)wv.y; wb[2]=(__bf16)wv.z; wb[3]=(__bf16)wv.w;
                *(bf16x4*)&Xl[srow][c0 + u * 4] = xb;
                *(bf16x4*)&Wl[srow][c0 + u * 4] = wb;
            }
            __syncthreads();
            #pragma unroll
            for (int ks = 0; ks < 2; ++ks) {
                const int ko = ks * 32 + quad * 8;
                bf16x8 bfr = *(const bf16x8*)&Wl[wave * 16 + l15][ko];
                #pragma unroll
                for (int i = 0; i < 4; ++i) {
                    bf16x8 afr = *(const bf16x8*)&Xl[i * 16 + l15][ko];
                    acc[i] = __builtin_amdgcn_mfma_f32_16x16x32_bf16(afr, bfr, acc[i], 0, 0, 0);
                }
            }
            __syncthreads();
        }
        const int mcol = wave * 16 + l15;
        #pragma unroll
        for (int i = 0; i < 4; ++i) {
            #pragma unroll
            for (int r = 0; r < 4; ++r) {
                int prow = base + i * 16 + quad * 4 + r;   // C/D: row=quad*4+reg
                if (prow < n)
                    Yo[(long)bucket[off + prow] * MD_ + mcol] = acc[i][r];
            }
        }
    }
}

// ---------------------------------------------------------------------------
// K2a: build dense combine matrix Wd[4096][576] bf16:
//      cols 0..511: softmax weights scattered at sel (dup-safe, serial)
//      cols 512..575: wmod[m] = sum_k w_k * (sum_s Yp[s][t,k,m] + cm_b[sel_k*64+m])
// ---------------------------------------------------------------------------
__global__ __launch_bounds__(256) void k_wdense(
    const float* __restrict__ Yp, const int* __restrict__ sel,
    const float* __restrict__ pw, const float* __restrict__ cm_b,
    __bf16* __restrict__ Wd)
{
    const int tid = threadIdx.x;
    const int tt = tid >> 6, m = tid & 63;
    const int t = blockIdx.x * 4 + tt;
    __shared__ float w_s[4][8];
    __shared__ int   sidx[4][8];
    __shared__ __align__(16) __bf16 row[4][KC_];

    if (m < 8) {
        w_s[tt][m]  = pw[t * 8 + m];
        sidx[tt][m] = sel[t * 8 + m];
    }
    __syncthreads();
    if (m == 0) {
        float mx = w_s[tt][0];
        #pragma unroll
        for (int k = 1; k < 8; ++k) mx = fmaxf(mx, w_s[tt][k]);
        float sum = 0.f;
        #pragma unroll
        for (int k = 0; k < 8; ++k) { float e = expf(w_s[tt][k] - mx); w_s[tt][k] = e; sum += e; }
        float inv = 1.f / sum;
        #pragma unroll
        for (int k = 0; k < 8; ++k) w_s[tt][k] *= inv;
    }
    __syncthreads();
    *(uint4*)&row[tt][m * 8] = make_uint4(0, 0, 0, 0);   // zero cols 0..511
    {
        const long YN = (long)T_ * K_ * MD_;
        float a = 0.f;
        #pragma unroll
        for (int k = 0; k < 8; ++k) {
            const long base = ((long)t * 8 + k) * MD_ + m;
            float y = cm_b[sidx[tt][k] * 64 + m];
            #pragma unroll
            for (int s = 0; s < NSPLIT; ++s) y += Yp[s * YN + base];
            a += w_s[tt][k] * y;
        }
        row[tt][512 + m] = (__bf16)a;
    }
    __syncthreads();
    if (m == 0) {
        #pragma unroll
        for (int k = 0; k < 8; ++k) {
            int c = sidx[tt][k];
            row[tt][c] = (__bf16)((float)row[tt][c] + w_s[tt][k]);  // dup-safe
        }
    }
    __syncthreads();
    const uint4* src = (const uint4*)&row[0][0];
    uint4* dst = (uint4*)(Wd + (long)blockIdx.x * 4 * KC_);
    for (int e = tid; e < 4 * KC_ * 2 / 16; e += 256) dst[e] = src[e];
}

// ---------------------------------------------------------------------------
// K2b: P[4096][576] bf16: P[f][c] = bp[c][f] (c<512) / adj[c-512][f].
// ---------------------------------------------------------------------------
__global__ __launch_bounds__(256) void k_buildP(
    const float* __restrict__ bp, const float* __restrict__ adj,
    __bf16* __restrict__ P)
{
    __shared__ __bf16 tile[64][72];
    const int tid = threadIdx.x;
    const int bx = blockIdx.x, f0 = blockIdx.y * 64;
    const float* src = (bx < 8) ? (bp + (long)bx * 64 * DFF_) : adj;
    for (int e = tid; e < 4096; e += 256) {
        int f = e & 63, c = e >> 6;
        tile[c][f] = (__bf16)src[(long)c * DFF_ + f0 + f];
    }
    __syncthreads();
    const int c0 = bx * 64;
    for (int e = tid; e < 4096; e += 256) {
        int c = e & 63, f = e >> 6;
        P[(long)(f0 + f) * KC_ + c0 + c] = tile[c][f];
    }
}

// ---------------------------------------------------------------------------
// K0: f32 -> bf16 convert for w2. n16 = n/16.
// ---------------------------------------------------------------------------
__global__ __launch_bounds__(256) void k_cvt(const float* __restrict__ src,
                                             __bf16* __restrict__ dst, int n16) {
    int i = blockIdx.x * 256 + threadIdx.x;
    if (i >= n16) return;
    const float4* s = (const float4*)src + (long)i * 4;
    float4 a = s[0], b = s[1], c = s[2], d = s[3];
    bf16x8 o0, o1;
    o0[0]=(__bf16)a.x; o0[1]=(__bf16)a.y; o0[2]=(__bf16)a.z; o0[3]=(__bf16)a.w;
    o0[4]=(__bf16)b.x; o0[5]=(__bf16)b.y; o0[6]=(__bf16)b.z; o0[7]=(__bf16)b.w;
    o1[0]=(__bf16)c.x; o1[1]=(__bf16)c.y; o1[2]=(__bf16)c.z; o1[3]=(__bf16)c.w;
    o1[4]=(__bf16)d.x; o1[5]=(__bf16)d.y; o1[6]=(__bf16)d.z; o1[7]=(__bf16)d.w;
    bf16x8* dp = (bf16x8*)dst + (long)i * 2;
    dp[0] = o0; dp[1] = o1;
}

// ---------------------------------------------------------------------------
// K2c: act[4096][4096] = gelu( Wd[4096][576] @ P[4096][576]^T )  bf16 out
// ---------------------------------------------------------------------------
__global__ __launch_bounds__(256) void k_actgemm(
    const __bf16* __restrict__ A, const __bf16* __restrict__ Bw,
    __bf16* __restrict__ act)
{
    __shared__ __align__(16) __bf16 sA[128 * 32];
    __shared__ __align__(16) __bf16 sB[128 * 32];
    const int tid  = threadIdx.x;
    const int tm   = blockIdx.y * 128, tn = blockIdx.x * 128;
    const int wave = tid >> 6, lane = tid & 63, quad = lane >> 4, l15 = lane & 15;
    const int wm   = (wave >> 1) * 64, wn = (wave & 1) * 64;

    f32x4 acc[4][4] = {};

    const int e    = tid * 8;
    const int srow = e >> 5;
    const int scol = e & 31;
    const __bf16* agp0 = A  + ((long)(tm + srow)      * KC_ + scol);
    const __bf16* agp1 = A  + ((long)(tm + 64 + srow) * KC_ + scol);
    const __bf16* bgp0 = Bw + ((long)(tn + srow)      * KC_ + scol);
    const __bf16* bgp1 = Bw + ((long)(tn + 64 + srow) * KC_ + scol);
    void* sa0 = (void*)(sA + e);
    void* sa1 = (void*)(sA + 2048 + e);
    void* sb0 = (void*)(sB + e);
    void* sb1 = (void*)(sB + 2048 + e);

    for (int kk = 0; kk < KC_; kk += 32) {
        async_ld16(agp0 + kk, sa0);
        async_ld16(agp1 + kk, sa1);
        async_ld16(bgp0 + kk, sb0);
        async_ld16(bgp1 + kk, sb1);
        __syncthreads();
        bf16x8 af[4], bf[4];
        #pragma unroll
        for (int i = 0; i < 4; ++i)
            af[i] = *(const bf16x8*)(sA + (wm + i * 16 + l15) * 32 + quad * 8);
        #pragma unroll
        for (int j = 0; j < 4; ++j)
            bf[j] = *(const bf16x8*)(sB + (wn + j * 16 + l15) * 32 + quad * 8);
        #pragma unroll
        for (int i = 0; i < 4; ++i)
            #pragma unroll
            for (int j = 0; j < 4; ++j)
                acc[i][j] = __builtin_amdgcn_mfma_f32_16x16x32_bf16(af[i], bf[j], acc[i][j], 0, 0, 0);
        __syncthreads();
    }

    #pragma unroll
    for (int j = 0; j < 4; ++j) {
        const int col = tn + wn + j * 16 + l15;
        #pragma unroll
        for (int i = 0; i < 4; ++i) {
            const int row = tm + wm + i * 16 + quad * 4;
            #pragma unroll
            for (int r = 0; r < 4; ++r)
                act[(long)(row + r) * DFF_ + col] = (__bf16)gelu_exact(acc[i][j][r]);
        }
    }
}

// ---------------------------------------------------------------------------
// K3: out[4096][1024] = act @ w2bf^T + w2_b.  BK=128 (4 x [128][32] sub-tiles,
//     one barrier per 64 MFMA): grid is 1 block/CU, so bigger K-tile amortizes
//     the vmcnt(0) barrier drain at zero occupancy cost.
// ---------------------------------------------------------------------------
__global__ __launch_bounds__(256) void k_outgemm(
    const __bf16* __restrict__ A, const __bf16* __restrict__ Bw,
    const float* __restrict__ bias, float* __restrict__ out)
{
    __shared__ __align__(16) __bf16 sA[128 * 128];
    __shared__ __align__(16) __bf16 sB[128 * 128];
    const int tid  = threadIdx.x;
    const int tm   = blockIdx.y * 128, tn = blockIdx.x * 128;
    const int wave = tid >> 6, lane = tid & 63, quad = lane >> 4, l15 = lane & 15;
    const int wm   = (wave >> 1) * 64, wn = (wave & 1) * 64;

    f32x4 acc[4][4] = {};

    const int e  = tid * 8;        // element within a 4KB issue
    const int r0 = e >> 5;         // row 0..63 within issue half
    const int cc = e & 31;

    for (int kk = 0; kk < DFF_; kk += 128) {
        #pragma unroll
        for (int s = 0; s < 4; ++s) {
            #pragma unroll
            for (int q = 0; q < 2; ++q) {
                async_ld16(A  + (long)(tm + q * 64 + r0) * DFF_ + kk + s * 32 + cc,
                           (void*)(sA + s * 4096 + q * 2048 + e));
                async_ld16(Bw + (long)(tn + q * 64 + r0) * DFF_ + kk + s * 32 + cc,
                           (void*)(sB + s * 4096 + q * 2048 + e));
            }
        }
        __syncthreads();
        #pragma unroll
        for (int s = 0; s < 4; ++s) {
            bf16x8 af[4], bf[4];
            #pragma unroll
            for (int i = 0; i < 4; ++i)
                af[i] = *(const bf16x8*)(sA + s * 4096 + (wm + i * 16 + l15) * 32 + quad * 8);
            #pragma unroll
            for (int j = 0; j < 4; ++j)
                bf[j] = *(const bf16x8*)(sB + s * 4096 + (wn + j * 16 + l15) * 32 + quad * 8);
            #pragma unroll
            for (int i = 0; i < 4; ++i)
                #pragma unroll
                for (int j = 0; j < 4; ++j)
                    acc[i][j] = __builtin_amdgcn_mfma_f32_16x16x32_bf16(af[i], bf[j], acc[i][j], 0, 0, 0);
        }
        __syncthreads();
    }

    #pragma unroll
    for (int j = 0; j < 4; ++j) {
        const int col = tn + wn + j * 16 + l15;
        const float bj = bias[col];
        #pragma unroll
        for (int i = 0; i < 4; ++i) {
            const int row = tm + wm + i * 16 + quad * 4;
            #pragma unroll
            for (int r = 0; r < 4; ++r)
                out[(long)(row + r) * 1024 + col] = acc[i][j][r] + bj;
        }
    }
}

// ---------------------------------------------------------------------------
extern "C" void kernel_launch(void* const* d_in, const int* in_sizes, int n_in,
                              void* d_out, int out_size, void* d_ws, size_t ws_size,
                              hipStream_t stream) {
    const float* x    = (const float*)d_in[0];
    const int*   sel  = (const int*)  d_in[1];
    const float* pw   = (const float*)d_in[2];
    const float* bp   = (const float*)d_in[3];
    const float* cm_w = (const float*)d_in[4];
    const float* cm_b = (const float*)d_in[5];
    const float* adj  = (const float*)d_in[6];
    const float* w2   = (const float*)d_in[7];
    const float* w2b  = (const float*)d_in[8];
    float* out = (float*)d_out;

    // ws (<=46MB): [0,32M) Yp (4x8MB partials), later act (32MB) — sequential
    //              [32M,37M) P | [37M,45M) w2bf | [45M,..) bins
    char* ws = (char*)d_ws;
    float*  Yp   = (float*)ws;
    __bf16* act  = (__bf16*)ws;
    __bf16* P    = (__bf16*)(ws + (size_t)32 * 1024 * 1024);
    __bf16* w2bf = (__bf16*)(ws + (size_t)37 * 1024 * 1024);
    char*  bins  = ws + (size_t)45 * 1024 * 1024;
    int* bucket  = (int*)bins;                 // 131072 B
    int* counts  = (int*)(bins + 131072);      // 2048 B
    int* cursor  = (int*)(bins + 133120);      // 2048 B
    int* offsets = (int*)(bins + 135168);      // 2052 B

    // d_out staging: Wd (4.72MB) — consumed by k_actgemm before out is written
    __bf16* Wd = (__bf16*)d_out;

    hipMemsetAsync(counts, 0, 4096, stream);   // counts + cursor
    k_hist   <<<128, 256, 0, stream>>>(sel, counts);
    k_scan   <<<1,   512, 0, stream>>>(counts, offsets, cursor);
    k_scatter<<<128, 256, 0, stream>>>(sel, cursor, bucket);
    k_selmod <<<dim3(POOL_, NSPLIT), 256, 0, stream>>>(x, cm_w, bucket, offsets, Yp);
    k_wdense <<<T_ / 4, 256, 0, stream>>>(Yp, sel, pw, cm_b, Wd);
    k_buildP <<<dim3(9, 64), 256, 0, stream>>>(bp, adj, P);
    k_cvt    <<<1024, 256, 0, stream>>>(w2, w2bf, DM_ * DFF_ / 16);
    k_actgemm<<<dim3(DFF_ / 128, T_ / 128), 256, 0, stream>>>(Wd, P, act);
    k_outgemm<<<dim3(DM_ / 128, T_ / 128), 256, 0, stream>>>(act, w2bf, w2b, out);
}

// Round 5
// 417.523 us; speedup vs baseline: 1.0568x; 1.0568x over previous
//
#include <hip/hip_runtime.h>
#include <math.h>

// ContextualNeuronPool: B=2,S=2048,K=8,POOL=512,DM=1024,DFF=4096,MD=64
// f32 inputs/outputs; internal GEMMs in bf16 MFMA.
#define T_    4096   // B*S tokens
#define K_    8
#define POOL_ 512
#define DM_   1024
#define DFF_  4096
#define MD_   64
#define KC_   576    // 512 (pool) + 64 (mod) combined contraction dim
#define NSPLIT 4     // k_selmod split-K factor
#define NCAP  256    // max pairs per pool (mean 64, sigma 8 -> 24 sigma margin)

typedef __bf16 bf16x8 __attribute__((ext_vector_type(8)));
typedef __bf16 bf16x4 __attribute__((ext_vector_type(4)));
typedef float  f32x4  __attribute__((ext_vector_type(4)));

typedef __attribute__((address_space(1))) const void g_void;
typedef __attribute__((address_space(3))) void s_void;

__device__ __forceinline__ void async_ld16(const void* g, void* s) {
    __builtin_amdgcn_global_load_lds((g_void*)g, (s_void*)s, 16, 0, 0);
}
__device__ __forceinline__ float gelu_exact(float g) {
    return 0.5f * g * (1.f + erff(g * 0.70710678118654752f));
}
__device__ __forceinline__ bf16x4 cvt4(float4 v) {
    bf16x4 o;
    o[0] = (__bf16)v.x; o[1] = (__bf16)v.y; o[2] = (__bf16)v.z; o[3] = (__bf16)v.w;
    return o;
}

// ---------------------------------------------------------------------------
// Binning: counting sort of the 32768 (token,k) pairs by pool index.
// ---------------------------------------------------------------------------
__global__ __launch_bounds__(256) void k_hist(const int* __restrict__ sel,
                                              int* __restrict__ counts) {
    int i = blockIdx.x * 256 + threadIdx.x;
    if (i < T_ * K_) atomicAdd(&counts[sel[i]], 1);
}

__global__ __launch_bounds__(512) void k_scan(const int* __restrict__ counts,
                                              int* __restrict__ offsets,
                                              int* __restrict__ cursor) {
    __shared__ int s[512];
    const int t = threadIdx.x;
    const int c = counts[t];
    s[t] = c;
    __syncthreads();
    for (int d = 1; d < 512; d <<= 1) {
        int v = (t >= d) ? s[t - d] : 0;
        __syncthreads();
        s[t] += v;
        __syncthreads();
    }
    offsets[t] = s[t] - c;
    cursor[t]  = s[t] - c;
    if (t == 511) offsets[512] = s[511];
}

__global__ __launch_bounds__(256) void k_scatter(const int* __restrict__ sel,
                                                 int* __restrict__ cursor,
                                                 int* __restrict__ bucket,
                                                 int* __restrict__ rank) {
    int i = blockIdx.x * 256 + threadIdx.x;
    if (i < T_ * K_) {
        int p = sel[i];
        int pos = atomicAdd(&cursor[p], 1);
        bucket[pos] = i;
        rank[i] = pos;
    }
}

// ---------------------------------------------------------------------------
// K1: expert-grouped sel_mod, split-K x4, COALESCED staging + SORTED Y writes.
//     Block (p, slice): Ys[slice][off+i][m] = dot(x[tok_i][k0:+256], cm_w[p*64+m][k0:+256])
//     Staging: 8 consecutive lanes cover one row -> 128B contiguous segments.
// ---------------------------------------------------------------------------
__global__ __launch_bounds__(256, 8) void k_selmod(
    const float* __restrict__ x, const float* __restrict__ cm_w,
    const int* __restrict__ bucket, const int* __restrict__ offsets,
    float* __restrict__ Yp)
{
    const int p     = blockIdx.x;
    const int slice = blockIdx.y;
    const int tid   = threadIdx.x;
    __shared__ int list[NCAP];
    __shared__ __align__(16) __bf16 Xl[64][72];
    __shared__ __align__(16) __bf16 Wl[64][72];

    const int off = offsets[p];
    const int n   = min(offsets[p + 1] - off, NCAP);
    if (n == 0) return;
    for (int i = tid; i < n; i += 256) list[i] = bucket[off + i] >> 3;  // token ids
    __syncthreads();

    const int wave = tid >> 6, lane = tid & 63, quad = lane >> 4, l15 = lane & 15;
    const int srow = tid >> 3;      // 0..31 (this thread stages rows srow, srow+32)
    const int part = tid & 7;       // 8 lanes x float4 = 128B contiguous per row
    const int k0   = slice * (DM_ / NSPLIT);

    const float* w0 = cm_w + (long)(p * 64 + srow)      * DM_ + k0;
    const float* w1 = cm_w + (long)(p * 64 + srow + 32) * DM_ + k0;
    float* Yo = Yp + (long)slice * ((long)T_ * K_ * MD_);

    for (int base = 0; base < n; base += 64) {
        f32x4 acc[4] = {};
        int li0 = base + srow;      if (li0 >= n) li0 = n - 1;   // clamp: dup stage row
        int li1 = base + srow + 32; if (li1 >= n) li1 = n - 1;
        const float* x0 = x + (long)list[li0] * DM_ + k0;
        const float* x1 = x + (long)list[li1] * DM_ + k0;

        for (int kc = 0; kc < DM_ / NSPLIT; kc += 64) {
            #pragma unroll
            for (int u = 0; u < 2; ++u) {
                const int c = kc + u * 32 + part * 4;
                float4 a0 = *(const float4*)(x0 + c);
                float4 a1 = *(const float4*)(x1 + c);
                float4 b0 = *(const float4*)(w0 + c);
                float4 b1 = *(const float4*)(w1 + c);
                const int lc = u * 32 + part * 4;
                *(bf16x4*)&Xl[srow     ][lc] = cvt4(a0);
                *(bf16x4*)&Xl[srow + 32][lc] = cvt4(a1);
                *(bf16x4*)&Wl[srow     ][lc] = cvt4(b0);
                *(bf16x4*)&Wl[srow + 32][lc] = cvt4(b1);
            }
            __syncthreads();
            #pragma unroll
            for (int ks = 0; ks < 2; ++ks) {
                const int ko = ks * 32 + quad * 8;
                bf16x8 bfr = *(const bf16x8*)&Wl[wave * 16 + l15][ko];
                #pragma unroll
                for (int i = 0; i < 4; ++i) {
                    bf16x8 afr = *(const bf16x8*)&Xl[i * 16 + l15][ko];
                    acc[i] = __builtin_amdgcn_mfma_f32_16x16x32_bf16(afr, bfr, acc[i], 0, 0, 0);
                }
            }
            __syncthreads();
        }
        const int mcol = wave * 16 + l15;
        #pragma unroll
        for (int i = 0; i < 4; ++i) {
            #pragma unroll
            for (int r = 0; r < 4; ++r) {
                int prow = base + i * 16 + quad * 4 + r;   // C/D: row=quad*4+reg
                if (prow < n)
                    Yo[(long)(off + prow) * MD_ + mcol] = acc[i][r];  // SORTED: coalesced
            }
        }
    }
}

// ---------------------------------------------------------------------------
// K2a: build dense combine matrix Wd[4096][576] bf16:
//      cols 0..511: softmax weights scattered at sel (dup-safe, serial)
//      cols 512..575: wmod[m] = sum_k w_k * (sum_s Yp[s][rank(t,k)][m] + cm_b[sel_k*64+m])
// ---------------------------------------------------------------------------
__global__ __launch_bounds__(256) void k_wdense(
    const float* __restrict__ Yp, const int* __restrict__ sel,
    const int* __restrict__ rank, const float* __restrict__ pw,
    const float* __restrict__ cm_b, __bf16* __restrict__ Wd)
{
    const int tid = threadIdx.x;
    const int tt = tid >> 6, m = tid & 63;
    const int t = blockIdx.x * 4 + tt;
    __shared__ float w_s[4][8];
    __shared__ int   sidx[4][8];
    __shared__ int   rnk[4][8];
    __shared__ __align__(16) __bf16 row[4][KC_];

    if (m < 8) {
        w_s[tt][m]  = pw[t * 8 + m];
        sidx[tt][m] = sel[t * 8 + m];
        rnk[tt][m]  = rank[t * 8 + m];
    }
    __syncthreads();
    if (m == 0) {
        float mx = w_s[tt][0];
        #pragma unroll
        for (int k = 1; k < 8; ++k) mx = fmaxf(mx, w_s[tt][k]);
        float sum = 0.f;
        #pragma unroll
        for (int k = 0; k < 8; ++k) { float e = expf(w_s[tt][k] - mx); w_s[tt][k] = e; sum += e; }
        float inv = 1.f / sum;
        #pragma unroll
        for (int k = 0; k < 8; ++k) w_s[tt][k] *= inv;
    }
    __syncthreads();
    *(uint4*)&row[tt][m * 8] = make_uint4(0, 0, 0, 0);   // zero cols 0..511
    {
        const long YN = (long)T_ * K_ * MD_;
        float a = 0.f;
        #pragma unroll
        for (int k = 0; k < 8; ++k) {
            const long base = (long)rnk[tt][k] * MD_ + m;
            float y = cm_b[sidx[tt][k] * 64 + m];
            #pragma unroll
            for (int s = 0; s < NSPLIT; ++s) y += Yp[s * YN + base];
            a += w_s[tt][k] * y;
        }
        row[tt][512 + m] = (__bf16)a;
    }
    __syncthreads();
    if (m == 0) {
        #pragma unroll
        for (int k = 0; k < 8; ++k) {
            int c = sidx[tt][k];
            row[tt][c] = (__bf16)((float)row[tt][c] + w_s[tt][k]);  // dup-safe
        }
    }
    __syncthreads();
    const uint4* src = (const uint4*)&row[0][0];
    uint4* dst = (uint4*)(Wd + (long)blockIdx.x * 4 * KC_);
    for (int e = tid; e < 4 * KC_ * 2 / 16; e += 256) dst[e] = src[e];
}

// ---------------------------------------------------------------------------
// K2b: P[4096][576] bf16: P[f][c] = bp[c][f] (c<512) / adj[c-512][f].
// ---------------------------------------------------------------------------
__global__ __launch_bounds__(256) void k_buildP(
    const float* __restrict__ bp, const float* __restrict__ adj,
    __bf16* __restrict__ P)
{
    __shared__ __bf16 tile[64][72];
    const int tid = threadIdx.x;
    const int bx = blockIdx.x, f0 = blockIdx.y * 64;
    const float* src = (bx < 8) ? (bp + (long)bx * 64 * DFF_) : adj;
    for (int e = tid; e < 4096; e += 256) {
        int f = e & 63, c = e >> 6;
        tile[c][f] = (__bf16)src[(long)c * DFF_ + f0 + f];
    }
    __syncthreads();
    const int c0 = bx * 64;
    for (int e = tid; e < 4096; e += 256) {
        int c = e & 63, f = e >> 6;
        P[(long)(f0 + f) * KC_ + c0 + c] = tile[c][f];
    }
}

// ---------------------------------------------------------------------------
// K0: f32 -> bf16 convert for w2. n16 = n/16.
// ---------------------------------------------------------------------------
__global__ __launch_bounds__(256) void k_cvt(const float* __restrict__ src,
                                             __bf16* __restrict__ dst, int n16) {
    int i = blockIdx.x * 256 + threadIdx.x;
    if (i >= n16) return;
    const float4* s = (const float4*)src + (long)i * 4;
    float4 a = s[0], b = s[1], c = s[2], d = s[3];
    bf16x8 o0, o1;
    o0[0]=(__bf16)a.x; o0[1]=(__bf16)a.y; o0[2]=(__bf16)a.z; o0[3]=(__bf16)a.w;
    o0[4]=(__bf16)b.x; o0[5]=(__bf16)b.y; o0[6]=(__bf16)b.z; o0[7]=(__bf16)b.w;
    o1[0]=(__bf16)c.x; o1[1]=(__bf16)c.y; o1[2]=(__bf16)c.z; o1[3]=(__bf16)c.w;
    o1[4]=(__bf16)d.x; o1[5]=(__bf16)d.y; o1[6]=(__bf16)d.z; o1[7]=(__bf16)d.w;
    bf16x8* dp = (bf16x8*)dst + (long)i * 2;
    dp[0] = o0; dp[1] = o1;
}

// ---------------------------------------------------------------------------
// K2c: act[4096][4096] = gelu( Wd[4096][576] @ P[4096][576]^T )  bf16 out
// ---------------------------------------------------------------------------
__global__ __launch_bounds__(256) void k_actgemm(
    const __bf16* __restrict__ A, const __bf16* __restrict__ Bw,
    __bf16* __restrict__ act)
{
    __shared__ __align__(16) __bf16 sA[128 * 32];
    __shared__ __align__(16) __bf16 sB[128 * 32];
    const int tid  = threadIdx.x;
    const int tm   = blockIdx.y * 128, tn = blockIdx.x * 128;
    const int wave = tid >> 6, lane = tid & 63, quad = lane >> 4, l15 = lane & 15;
    const int wm   = (wave >> 1) * 64, wn = (wave & 1) * 64;

    f32x4 acc[4][4] = {};

    const int e    = tid * 8;
    const int srow = e >> 5;
    const int scol = e & 31;
    const __bf16* agp0 = A  + ((long)(tm + srow)      * KC_ + scol);
    const __bf16* agp1 = A  + ((long)(tm + 64 + srow) * KC_ + scol);
    const __bf16* bgp0 = Bw + ((long)(tn + srow)      * KC_ + scol);
    const __bf16* bgp1 = Bw + ((long)(tn + 64 + srow) * KC_ + scol);
    void* sa0 = (void*)(sA + e);
    void* sa1 = (void*)(sA + 2048 + e);
    void* sb0 = (void*)(sB + e);
    void* sb1 = (void*)(sB + 2048 + e);

    for (int kk = 0; kk < KC_; kk += 32) {
        async_ld16(agp0 + kk, sa0);
        async_ld16(agp1 + kk, sa1);
        async_ld16(bgp0 + kk, sb0);
        async_ld16(bgp1 + kk, sb1);
        __syncthreads();
        bf16x8 af[4], bf[4];
        #pragma unroll
        for (int i = 0; i < 4; ++i)
            af[i] = *(const bf16x8*)(sA + (wm + i * 16 + l15) * 32 + quad * 8);
        #pragma unroll
        for (int j = 0; j < 4; ++j)
            bf[j] = *(const bf16x8*)(sB + (wn + j * 16 + l15) * 32 + quad * 8);
        #pragma unroll
        for (int i = 0; i < 4; ++i)
            #pragma unroll
            for (int j = 0; j < 4; ++j)
                acc[i][j] = __builtin_amdgcn_mfma_f32_16x16x32_bf16(af[i], bf[j], acc[i][j], 0, 0, 0);
        __syncthreads();
    }

    #pragma unroll
    for (int j = 0; j < 4; ++j) {
        const int col = tn + wn + j * 16 + l15;
        #pragma unroll
        for (int i = 0; i < 4; ++i) {
            const int row = tm + wm + i * 16 + quad * 4;
            #pragma unroll
            for (int r = 0; r < 4; ++r)
                act[(long)(row + r) * DFF_ + col] = (__bf16)gelu_exact(acc[i][j][r]);
        }
    }
}

// ---------------------------------------------------------------------------
// K3: out[4096][1024] = act @ w2bf^T + w2_b.  BK=128 (4 x [128][32] sub-tiles,
//     one barrier per 64 MFMA); 1 block/CU so big K-tile is free.
// ---------------------------------------------------------------------------
__global__ __launch_bounds__(256) void k_outgemm(
    const __bf16* __restrict__ A, const __bf16* __restrict__ Bw,
    const float* __restrict__ bias, float* __restrict__ out)
{
    __shared__ __align__(16) __bf16 sA[128 * 128];
    __shared__ __align__(16) __bf16 sB[128 * 128];
    const int tid  = threadIdx.x;
    const int tm   = blockIdx.y * 128, tn = blockIdx.x * 128;
    const int wave = tid >> 6, lane = tid & 63, quad = lane >> 4, l15 = lane & 15;
    const int wm   = (wave >> 1) * 64, wn = (wave & 1) * 64;

    f32x4 acc[4][4] = {};

    const int e  = tid * 8;
    const int r0 = e >> 5;
    const int cc = e & 31;

    for (int kk = 0; kk < DFF_; kk += 128) {
        #pragma unroll
        for (int s = 0; s < 4; ++s) {
            #pragma unroll
            for (int q = 0; q < 2; ++q) {
                async_ld16(A  + (long)(tm + q * 64 + r0) * DFF_ + kk + s * 32 + cc,
                           (void*)(sA + s * 4096 + q * 2048 + e));
                async_ld16(Bw + (long)(tn + q * 64 + r0) * DFF_ + kk + s * 32 + cc,
                           (void*)(sB + s * 4096 + q * 2048 + e));
            }
        }
        __syncthreads();
        #pragma unroll
        for (int s = 0; s < 4; ++s) {
            bf16x8 af[4], bf[4];
            #pragma unroll
            for (int i = 0; i < 4; ++i)
                af[i] = *(const bf16x8*)(sA + s * 4096 + (wm + i * 16 + l15) * 32 + quad * 8);
            #pragma unroll
            for (int j = 0; j < 4; ++j)
                bf[j] = *(const bf16x8*)(sB + s * 4096 + (wn + j * 16 + l15) * 32 + quad * 8);
            #pragma unroll
            for (int i = 0; i < 4; ++i)
                #pragma unroll
                for (int j = 0; j < 4; ++j)
                    acc[i][j] = __builtin_amdgcn_mfma_f32_16x16x32_bf16(af[i], bf[j], acc[i][j], 0, 0, 0);
        }
        __syncthreads();
    }

    #pragma unroll
    for (int j = 0; j < 4; ++j) {
        const int col = tn + wn + j * 16 + l15;
        const float bj = bias[col];
        #pragma unroll
        for (int i = 0; i < 4; ++i) {
            const int row = tm + wm + i * 16 + quad * 4;
            #pragma unroll
            for (int r = 0; r < 4; ++r)
                out[(long)(row + r) * 1024 + col] = acc[i][j][r] + bj;
        }
    }
}

// ---------------------------------------------------------------------------
extern "C" void kernel_launch(void* const* d_in, const int* in_sizes, int n_in,
                              void* d_out, int out_size, void* d_ws, size_t ws_size,
                              hipStream_t stream) {
    const float* x    = (const float*)d_in[0];
    const int*   sel  = (const int*)  d_in[1];
    const float* pw   = (const float*)d_in[2];
    const float* bp   = (const float*)d_in[3];
    const float* cm_w = (const float*)d_in[4];
    const float* cm_b = (const float*)d_in[5];
    const float* adj  = (const float*)d_in[6];
    const float* w2   = (const float*)d_in[7];
    const float* w2b  = (const float*)d_in[8];
    float* out = (float*)d_out;

    // ws (<=46MB): [0,32M) Yp (4x8MB sorted partials), later act (32MB) — sequential
    //              [32M,37M) P | [37M,45M) w2bf | [45M,..) bins
    char* ws = (char*)d_ws;
    float*  Yp   = (float*)ws;
    __bf16* act  = (__bf16*)ws;
    __bf16* P    = (__bf16*)(ws + (size_t)32 * 1024 * 1024);
    __bf16* w2bf = (__bf16*)(ws + (size_t)37 * 1024 * 1024);
    char*  bins  = ws + (size_t)45 * 1024 * 1024;
    int* bucket  = (int*)bins;                 // 131072 B
    int* rank    = (int*)(bins + 131072);      // 131072 B
    int* counts  = (int*)(bins + 262144);      // 2048 B
    int* cursor  = (int*)(bins + 264192);      // 2048 B
    int* offsets = (int*)(bins + 266240);      // 2052 B

    // d_out staging: Wd (4.72MB) — consumed by k_actgemm before out is written
    __bf16* Wd = (__bf16*)d_out;

    hipMemsetAsync(counts, 0, 4096, stream);   // counts + cursor
    k_hist   <<<128, 256, 0, stream>>>(sel, counts);
    k_scan   <<<1,   512, 0, stream>>>(counts, offsets, cursor);
    k_scatter<<<128, 256, 0, stream>>>(sel, cursor, bucket, rank);
    k_selmod <<<dim3(POOL_, NSPLIT), 256, 0, stream>>>(x, cm_w, bucket, offsets, Yp);
    k_wdense <<<T_ / 4, 256, 0, stream>>>(Yp, sel, rank, pw, cm_b, Wd);
    k_buildP <<<dim3(9, 64), 256, 0, stream>>>(bp, adj, P);
    k_cvt    <<<1024, 256, 0, stream>>>(w2, w2bf, DM_ * DFF_ / 16);
    k_actgemm<<<dim3(DFF_ / 128, T_ / 128), 256, 0, stream>>>(Wd, P, act);
    k_outgemm<<<dim3(DM_ / 128, T_ / 128), 256, 0, stream>>>(act, w2bf, w2b, out);
}

// Round 6
// 414.902 us; speedup vs baseline: 1.0635x; 1.0063x over previous
//
#include <hip/hip_runtime.h>
#include <math.h>

// ContextualNeuronPool: B=2,S=2048,K=8,POOL=512,DM=1024,DFF=4096,MD=64
// f32 inputs/outputs; internal GEMMs in bf16 MFMA.
#define T_    4096   // B*S tokens
#define K_    8
#define POOL_ 512
#define DM_   1024
#define DFF_  4096
#define MD_   64
#define KC_   576    // 512 (pool) + 64 (mod) combined contraction dim
#define NCAP  256    // max pairs per pool (mean 64, sigma 8)

typedef __bf16 bf16x8 __attribute__((ext_vector_type(8)));
typedef __bf16 bf16x4 __attribute__((ext_vector_type(4)));
typedef float  f32x4  __attribute__((ext_vector_type(4)));

typedef __attribute__((address_space(1))) const void g_void;
typedef __attribute__((address_space(3))) void s_void;

__device__ __forceinline__ void async_ld16(const void* g, void* s) {
    __builtin_amdgcn_global_load_lds((g_void*)g, (s_void*)s, 16, 0, 0);
}
__device__ __forceinline__ float gelu_exact(float g) {
    return 0.5f * g * (1.f + erff(g * 0.70710678118654752f));
}
__device__ __forceinline__ bf16x4 cvt4(float4 v) {
    bf16x4 o;
    o[0] = (__bf16)v.x; o[1] = (__bf16)v.y; o[2] = (__bf16)v.z; o[3] = (__bf16)v.w;
    return o;
}

// ---------------------------------------------------------------------------
// Binning: counting sort of the 32768 (token,k) pairs by pool index.
// ---------------------------------------------------------------------------
__global__ __launch_bounds__(256) void k_hist(const int* __restrict__ sel,
                                              int* __restrict__ counts) {
    int i = blockIdx.x * 256 + threadIdx.x;
    if (i < T_ * K_) atomicAdd(&counts[sel[i]], 1);
}

__global__ __launch_bounds__(512) void k_scan(const int* __restrict__ counts,
                                              int* __restrict__ offsets,
                                              int* __restrict__ cursor) {
    __shared__ int s[512];
    const int t = threadIdx.x;
    const int c = counts[t];
    s[t] = c;
    __syncthreads();
    for (int d = 1; d < 512; d <<= 1) {
        int v = (t >= d) ? s[t - d] : 0;
        __syncthreads();
        s[t] += v;
        __syncthreads();
    }
    offsets[t] = s[t] - c;
    cursor[t]  = s[t] - c;
    if (t == 511) offsets[512] = s[511];
}

__global__ __launch_bounds__(256) void k_scatter(const int* __restrict__ sel,
                                                 int* __restrict__ cursor,
                                                 int* __restrict__ bucket,
                                                 int* __restrict__ rank) {
    int i = blockIdx.x * 256 + threadIdx.x;
    if (i < T_ * K_) {
        int p = sel[i];
        int pos = atomicAdd(&cursor[p], 1);
        bucket[pos] = i;
        rank[i] = pos;
    }
}

// ---------------------------------------------------------------------------
// K0: f32 -> bf16 convert (used for w2 and x). n16 = n/16.
// ---------------------------------------------------------------------------
__global__ __launch_bounds__(256) void k_cvt(const float* __restrict__ src,
                                             __bf16* __restrict__ dst, int n16) {
    int i = blockIdx.x * 256 + threadIdx.x;
    if (i >= n16) return;
    const float4* s = (const float4*)src + (long)i * 4;
    float4 a = s[0], b = s[1], c = s[2], d = s[3];
    bf16x8 o0, o1;
    o0[0]=(__bf16)a.x; o0[1]=(__bf16)a.y; o0[2]=(__bf16)a.z; o0[3]=(__bf16)a.w;
    o0[4]=(__bf16)b.x; o0[5]=(__bf16)b.y; o0[6]=(__bf16)b.z; o0[7]=(__bf16)b.w;
    o1[0]=(__bf16)c.x; o1[1]=(__bf16)c.y; o1[2]=(__bf16)c.z; o1[3]=(__bf16)c.w;
    o1[4]=(__bf16)d.x; o1[5]=(__bf16)d.y; o1[6]=(__bf16)d.z; o1[7]=(__bf16)d.w;
    bf16x8* dp = (bf16x8*)dst + (long)i * 2;
    dp[0] = o0; dp[1] = o1;
}

// ---------------------------------------------------------------------------
// K1 v3: expert-grouped sel_mod, N-SPLIT x4 (16 m-cols per block), full K.
//   Block (p, ms): W rows p*64+ms*16 .. +16 = 64KB CONTIGUOUS cm_w, staged to
//   LDS once (bf16, sequential 4 streams/wave). X chunks staged per kc from
//   pre-converted bf16 x. Y written sorted (no partials).
// ---------------------------------------------------------------------------
__global__ __launch_bounds__(256) void k_selmod(
    const __bf16* __restrict__ xb, const float* __restrict__ cm_w,
    const int* __restrict__ bucket, const int* __restrict__ offsets,
    float* __restrict__ Y)
{
    const int p   = blockIdx.x;
    const int ms  = blockIdx.y;           // m-slice: cols ms*16 .. +16
    const int tid = threadIdx.x;
    __shared__ int list[NCAP];
    __shared__ __align__(16) __bf16 Wl[16][1032];  // 16 rows x 1024 K (+8 pad)
    __shared__ __align__(16) __bf16 Xl[64][72];    // 64 rows x 64 K chunk (+8 pad)

    const int off = offsets[p];
    const int n   = min(offsets[p + 1] - off, NCAP);
    if (n == 0) return;
    for (int i = tid; i < n; i += 256) list[i] = bucket[off + i] >> 3;  // token ids

    // stage W: 16 rows x 1024 f32, sequential (each wave: 4 row-streams, 256B steps)
    {
        const int wr = tid >> 4;          // 0..15
        const int wl = tid & 15;
        const float* wsrc = cm_w + (long)(p * 64 + ms * 16 + wr) * DM_;
        #pragma unroll
        for (int j = 0; j < 16; ++j) {
            float4 v = *(const float4*)(wsrc + j * 64 + wl * 4);
            *(bf16x4*)&Wl[wr][j * 64 + wl * 4] = cvt4(v);
        }
    }
    __syncthreads();

    const int wave = tid >> 6, lane = tid & 63, quad = lane >> 4, l15 = lane & 15;
    const int srow = tid >> 3;            // 0..31 (stages rows srow, srow+32)
    const int part = tid & 7;             // 8 lanes x bf16x8 = 128B per row

    for (int base = 0; base < n; base += 64) {
        f32x4 acc = {};
        int li0 = base + srow;      if (li0 >= n) li0 = n - 1;   // clamp: dup row
        int li1 = base + srow + 32; if (li1 >= n) li1 = n - 1;
        const __bf16* x0 = xb + (long)list[li0] * DM_ + part * 8;
        const __bf16* x1 = xb + (long)list[li1] * DM_ + part * 8;

        for (int kc = 0; kc < DM_; kc += 64) {
            *(bf16x8*)&Xl[srow     ][part * 8] = *(const bf16x8*)(x0 + kc);
            *(bf16x8*)&Xl[srow + 32][part * 8] = *(const bf16x8*)(x1 + kc);
            __syncthreads();
            #pragma unroll
            for (int ks = 0; ks < 2; ++ks) {
                const int ko = ks * 32 + quad * 8;
                bf16x8 bfr = *(const bf16x8*)&Wl[l15][kc + ko];       // B: 16 cols
                bf16x8 afr = *(const bf16x8*)&Xl[wave * 16 + l15][ko]; // A: 16 rows
                acc = __builtin_amdgcn_mfma_f32_16x16x32_bf16(afr, bfr, acc, 0, 0, 0);
            }
            __syncthreads();
        }
        #pragma unroll
        for (int r = 0; r < 4; ++r) {
            int prow = base + wave * 16 + quad * 4 + r;   // C/D: row=quad*4+reg
            if (prow < n)
                Y[(long)(off + prow) * MD_ + ms * 16 + l15] = acc[r];  // sorted
        }
    }
}

// ---------------------------------------------------------------------------
// K2a: build dense combine matrix Wd[4096][576] bf16:
//      cols 0..511: softmax weights scattered at sel (dup-safe, serial)
//      cols 512..575: wmod[m] = sum_k w_k * (Y[rank(t,k)][m] + cm_b[sel_k*64+m])
// ---------------------------------------------------------------------------
__global__ __launch_bounds__(256) void k_wdense(
    const float* __restrict__ Y, const int* __restrict__ sel,
    const int* __restrict__ rank, const float* __restrict__ pw,
    const float* __restrict__ cm_b, __bf16* __restrict__ Wd)
{
    const int tid = threadIdx.x;
    const int tt = tid >> 6, m = tid & 63;
    const int t = blockIdx.x * 4 + tt;
    __shared__ float w_s[4][8];
    __shared__ int   sidx[4][8];
    __shared__ int   rnk[4][8];
    __shared__ __align__(16) __bf16 row[4][KC_];

    if (m < 8) {
        w_s[tt][m]  = pw[t * 8 + m];
        sidx[tt][m] = sel[t * 8 + m];
        rnk[tt][m]  = rank[t * 8 + m];
    }
    __syncthreads();
    if (m == 0) {
        float mx = w_s[tt][0];
        #pragma unroll
        for (int k = 1; k < 8; ++k) mx = fmaxf(mx, w_s[tt][k]);
        float sum = 0.f;
        #pragma unroll
        for (int k = 0; k < 8; ++k) { float e = expf(w_s[tt][k] - mx); w_s[tt][k] = e; sum += e; }
        float inv = 1.f / sum;
        #pragma unroll
        for (int k = 0; k < 8; ++k) w_s[tt][k] *= inv;
    }
    __syncthreads();
    *(uint4*)&row[tt][m * 8] = make_uint4(0, 0, 0, 0);   // zero cols 0..511
    {
        float a = 0.f;
        #pragma unroll
        for (int k = 0; k < 8; ++k) {
            float y = cm_b[sidx[tt][k] * 64 + m] + Y[(long)rnk[tt][k] * MD_ + m];
            a += w_s[tt][k] * y;
        }
        row[tt][512 + m] = (__bf16)a;
    }
    __syncthreads();
    if (m == 0) {
        #pragma unroll
        for (int k = 0; k < 8; ++k) {
            int c = sidx[tt][k];
            row[tt][c] = (__bf16)((float)row[tt][c] + w_s[tt][k]);  // dup-safe
        }
    }
    __syncthreads();
    const uint4* src = (const uint4*)&row[0][0];
    uint4* dst = (uint4*)(Wd + (long)blockIdx.x * 4 * KC_);
    for (int e = tid; e < 4 * KC_ * 2 / 16; e += 256) dst[e] = src[e];
}

// ---------------------------------------------------------------------------
// K2b: P[4096][576] bf16: P[f][c] = bp[c][f] (c<512) / adj[c-512][f].
// ---------------------------------------------------------------------------
__global__ __launch_bounds__(256) void k_buildP(
    const float* __restrict__ bp, const float* __restrict__ adj,
    __bf16* __restrict__ P)
{
    __shared__ __bf16 tile[64][72];
    const int tid = threadIdx.x;
    const int bx = blockIdx.x, f0 = blockIdx.y * 64;
    const float* src = (bx < 8) ? (bp + (long)bx * 64 * DFF_) : adj;
    for (int e = tid; e < 4096; e += 256) {
        int f = e & 63, c = e >> 6;
        tile[c][f] = (__bf16)src[(long)c * DFF_ + f0 + f];
    }
    __syncthreads();
    const int c0 = bx * 64;
    for (int e = tid; e < 4096; e += 256) {
        int c = e & 63, f = e >> 6;
        P[(long)(f0 + f) * KC_ + c0 + c] = tile[c][f];
    }
}

// ---------------------------------------------------------------------------
// K2c: act[4096][4096] = gelu( Wd[4096][576] @ P[4096][576]^T )  bf16 out
// ---------------------------------------------------------------------------
__global__ __launch_bounds__(256) void k_actgemm(
    const __bf16* __restrict__ A, const __bf16* __restrict__ Bw,
    __bf16* __restrict__ act)
{
    __shared__ __align__(16) __bf16 sA[128 * 32];
    __shared__ __align__(16) __bf16 sB[128 * 32];
    const int tid  = threadIdx.x;
    const int tm   = blockIdx.y * 128, tn = blockIdx.x * 128;
    const int wave = tid >> 6, lane = tid & 63, quad = lane >> 4, l15 = lane & 15;
    const int wm   = (wave >> 1) * 64, wn = (wave & 1) * 64;

    f32x4 acc[4][4] = {};

    const int e    = tid * 8;
    const int srow = e >> 5;
    const int scol = e & 31;
    const __bf16* agp0 = A  + ((long)(tm + srow)      * KC_ + scol);
    const __bf16* agp1 = A  + ((long)(tm + 64 + srow) * KC_ + scol);
    const __bf16* bgp0 = Bw + ((long)(tn + srow)      * KC_ + scol);
    const __bf16* bgp1 = Bw + ((long)(tn + 64 + srow) * KC_ + scol);
    void* sa0 = (void*)(sA + e);
    void* sa1 = (void*)(sA + 2048 + e);
    void* sb0 = (void*)(sB + e);
    void* sb1 = (void*)(sB + 2048 + e);

    for (int kk = 0; kk < KC_; kk += 32) {
        async_ld16(agp0 + kk, sa0);
        async_ld16(agp1 + kk, sa1);
        async_ld16(bgp0 + kk, sb0);
        async_ld16(bgp1 + kk, sb1);
        __syncthreads();
        bf16x8 af[4], bf[4];
        #pragma unroll
        for (int i = 0; i < 4; ++i)
            af[i] = *(const bf16x8*)(sA + (wm + i * 16 + l15) * 32 + quad * 8);
        #pragma unroll
        for (int j = 0; j < 4; ++j)
            bf[j] = *(const bf16x8*)(sB + (wn + j * 16 + l15) * 32 + quad * 8);
        #pragma unroll
        for (int i = 0; i < 4; ++i)
            #pragma unroll
            for (int j = 0; j < 4; ++j)
                acc[i][j] = __builtin_amdgcn_mfma_f32_16x16x32_bf16(af[i], bf[j], acc[i][j], 0, 0, 0);
        __syncthreads();
    }

    #pragma unroll
    for (int j = 0; j < 4; ++j) {
        const int col = tn + wn + j * 16 + l15;
        #pragma unroll
        for (int i = 0; i < 4; ++i) {
            const int row = tm + wm + i * 16 + quad * 4;
            #pragma unroll
            for (int r = 0; r < 4; ++r)
                act[(long)(row + r) * DFF_ + col] = (__bf16)gelu_exact(acc[i][j][r]);
        }
    }
}

// ---------------------------------------------------------------------------
// K3: out[4096][1024] = act @ w2bf^T + w2_b.  BK=128; 1 block/CU.
// ---------------------------------------------------------------------------
__global__ __launch_bounds__(256) void k_outgemm(
    const __bf16* __restrict__ A, const __bf16* __restrict__ Bw,
    const float* __restrict__ bias, float* __restrict__ out)
{
    __shared__ __align__(16) __bf16 sA[128 * 128];
    __shared__ __align__(16) __bf16 sB[128 * 128];
    const int tid  = threadIdx.x;
    const int tm   = blockIdx.y * 128, tn = blockIdx.x * 128;
    const int wave = tid >> 6, lane = tid & 63, quad = lane >> 4, l15 = lane & 15;
    const int wm   = (wave >> 1) * 64, wn = (wave & 1) * 64;

    f32x4 acc[4][4] = {};

    const int e  = tid * 8;
    const int r0 = e >> 5;
    const int cc = e & 31;

    for (int kk = 0; kk < DFF_; kk += 128) {
        #pragma unroll
        for (int s = 0; s < 4; ++s) {
            #pragma unroll
            for (int q = 0; q < 2; ++q) {
                async_ld16(A  + (long)(tm + q * 64 + r0) * DFF_ + kk + s * 32 + cc,
                           (void*)(sA + s * 4096 + q * 2048 + e));
                async_ld16(Bw + (long)(tn + q * 64 + r0) * DFF_ + kk + s * 32 + cc,
                           (void*)(sB + s * 4096 + q * 2048 + e));
            }
        }
        __syncthreads();
        #pragma unroll
        for (int s = 0; s < 4; ++s) {
            bf16x8 af[4], bf[4];
            #pragma unroll
            for (int i = 0; i < 4; ++i)
                af[i] = *(const bf16x8*)(sA + s * 4096 + (wm + i * 16 + l15) * 32 + quad * 8);
            #pragma unroll
            for (int j = 0; j < 4; ++j)
                bf[j] = *(const bf16x8*)(sB + s * 4096 + (wn + j * 16 + l15) * 32 + quad * 8);
            #pragma unroll
            for (int i = 0; i < 4; ++i)
                #pragma unroll
                for (int j = 0; j < 4; ++j)
                    acc[i][j] = __builtin_amdgcn_mfma_f32_16x16x32_bf16(af[i], bf[j], acc[i][j], 0, 0, 0);
        }
        __syncthreads();
    }

    #pragma unroll
    for (int j = 0; j < 4; ++j) {
        const int col = tn + wn + j * 16 + l15;
        const float bj = bias[col];
        #pragma unroll
        for (int i = 0; i < 4; ++i) {
            const int row = tm + wm + i * 16 + quad * 4;
            #pragma unroll
            for (int r = 0; r < 4; ++r)
                out[(long)(row + r) * 1024 + col] = acc[i][j][r] + bj;
        }
    }
}

// ---------------------------------------------------------------------------
extern "C" void kernel_launch(void* const* d_in, const int* in_sizes, int n_in,
                              void* d_out, int out_size, void* d_ws, size_t ws_size,
                              hipStream_t stream) {
    const float* x    = (const float*)d_in[0];
    const int*   sel  = (const int*)  d_in[1];
    const float* pw   = (const float*)d_in[2];
    const float* bp   = (const float*)d_in[3];
    const float* cm_w = (const float*)d_in[4];
    const float* cm_b = (const float*)d_in[5];
    const float* adj  = (const float*)d_in[6];
    const float* w2   = (const float*)d_in[7];
    const float* w2b  = (const float*)d_in[8];
    float* out = (float*)d_out;

    // ws: [0,8M) x_bf (consumed by k_selmod, then overwritten by act)
    //     [0,32M) act | [32M,37M) P | [37M,45M) w2bf | [45M,..) bins
    char* ws = (char*)d_ws;
    __bf16* x_bf = (__bf16*)ws;
    __bf16* act  = (__bf16*)ws;
    __bf16* P    = (__bf16*)(ws + (size_t)32 * 1024 * 1024);
    __bf16* w2bf = (__bf16*)(ws + (size_t)37 * 1024 * 1024);
    char*  bins  = ws + (size_t)45 * 1024 * 1024;
    int* bucket  = (int*)bins;                 // 131072 B
    int* rank    = (int*)(bins + 131072);      // 131072 B
    int* counts  = (int*)(bins + 262144);      // 2048 B
    int* cursor  = (int*)(bins + 264192);      // 2048 B
    int* offsets = (int*)(bins + 266240);      // 2052 B

    // d_out staging (consumed before k_outgemm): Y f32 8M | Wd 4.72M
    float*  Y  = (float*)d_out;
    __bf16* Wd = (__bf16*)((char*)d_out + (size_t)8 * 1024 * 1024);

    hipMemsetAsync(counts, 0, 4096, stream);   // counts + cursor
    k_hist   <<<128, 256, 0, stream>>>(sel, counts);
    k_scan   <<<1,   512, 0, stream>>>(counts, offsets, cursor);
    k_scatter<<<128, 256, 0, stream>>>(sel, cursor, bucket, rank);
    k_cvt    <<<1024, 256, 0, stream>>>(x, x_bf, T_ * DM_ / 16);
    k_selmod <<<dim3(POOL_, 4), 256, 0, stream>>>(x_bf, cm_w, bucket, offsets, Y);
    k_wdense <<<T_ / 4, 256, 0, stream>>>(Y, sel, rank, pw, cm_b, Wd);
    k_buildP <<<dim3(9, 64), 256, 0, stream>>>(bp, adj, P);
    k_cvt    <<<1024, 256, 0, stream>>>(w2, w2bf, DM_ * DFF_ / 16);
    k_actgemm<<<dim3(DFF_ / 128, T_ / 128), 256, 0, stream>>>(Wd, P, act);
    k_outgemm<<<dim3(DM_ / 128, T_ / 128), 256, 0, stream>>>(act, w2bf, w2b, out);
}